// Round 1
// baseline (51.944 us; speedup 1.0000x reference)
//
#include <hip/hip_runtime.h>
#include <math.h>

#define THREADS 256
#define NSLOT 5
#define EPSF 1e-8f

__global__ __launch_bounds__(THREADS) void mb_kernel(
    const float* __restrict__ query,    // B x D
    const int*   __restrict__ labels,   // B
    const float* __restrict__ mkeys,    // C x S x D
    const float* __restrict__ mvals,    // C x S x D
    const float* __restrict__ qscores,  // C x S
    const int*   __restrict__ topk_p,   // scalar
    float* __restrict__ out_ret,        // B x D
    float* __restrict__ out_w,          // B
    int D)
{
    const int i    = blockIdx.x;
    const int tid  = threadIdx.x;
    const int lane = tid & 63;
    const int wave = tid >> 6;
    const int c    = labels[i];

    int k = topk_p[0];
    if (k > NSLOT) k = NSLOT;
    if (k < 1) k = 1;

    const int n4 = D >> 2;                       // 512 float4 per row
    const float4* q4 = reinterpret_cast<const float4*>(query) + (size_t)i * n4;
    const float4* k4 = reinterpret_cast<const float4*>(mkeys) + (size_t)c * NSLOT * n4;
    const float4* v4 = reinterpret_cast<const float4*>(mvals) + (size_t)c * NSLOT * n4;
    float4* o4 = reinterpret_cast<float4*>(out_ret) + (size_t)i * n4;

    // ---- pass 1: qq, dot[s] = q.key_s, kk[s] = |key_s|^2 in one sweep ----
    float qq = 0.f;
    float dot[NSLOT], kk[NSLOT];
#pragma unroll
    for (int s = 0; s < NSLOT; ++s) { dot[s] = 0.f; kk[s] = 0.f; }

    for (int idx = tid; idx < n4; idx += THREADS) {
        float4 q = q4[idx];
        qq += q.x * q.x + q.y * q.y + q.z * q.z + q.w * q.w;
#pragma unroll
        for (int s = 0; s < NSLOT; ++s) {
            float4 kv = k4[s * n4 + idx];
            dot[s] += q.x * kv.x + q.y * kv.y + q.z * kv.z + q.w * kv.w;
            kk[s]  += kv.x * kv.x + kv.y * kv.y + kv.z * kv.z + kv.w * kv.w;
        }
    }

    // ---- wave-level shuffle reduction (64 lanes) ----
#pragma unroll
    for (int off = 32; off > 0; off >>= 1) {
        qq += __shfl_down(qq, off);
#pragma unroll
        for (int s = 0; s < NSLOT; ++s) {
            dot[s] += __shfl_down(dot[s], off);
            kk[s]  += __shfl_down(kk[s], off);
        }
    }

    __shared__ float red[THREADS / 64][11];
    __shared__ float sh_attn[NSLOT];
    __shared__ int   sh_idx[NSLOT];
    __shared__ int   sh_hit;

    if (lane == 0) {
        red[wave][0] = qq;
#pragma unroll
        for (int s = 0; s < NSLOT; ++s) {
            red[wave][1 + s] = dot[s];
            red[wave][6 + s] = kk[s];
        }
    }
    __syncthreads();

    if (tid == 0) {
        float tqq = 0.f, tdot[NSLOT], tkk[NSLOT];
#pragma unroll
        for (int s = 0; s < NSLOT; ++s) { tdot[s] = 0.f; tkk[s] = 0.f; }
        for (int w = 0; w < THREADS / 64; ++w) {
            tqq += red[w][0];
#pragma unroll
            for (int s = 0; s < NSLOT; ++s) {
                tdot[s] += red[w][1 + s];
                tkk[s]  += red[w][6 + s];
            }
        }

        float qn = fmaxf(sqrtf(tqq), EPSF);

        float scores[NSLOT];
        float ssum = 0.f;
#pragma unroll
        for (int s = 0; s < NSLOT; ++s) {
            scores[s] = qscores[(size_t)c * NSLOT + s];
            ssum += scores[s];
        }

        float comb[NSLOT];
#pragma unroll
        for (int s = 0; s < NSLOT; ++s) {
            float kn = fmaxf(sqrtf(tkk[s]), EPSF);
            comb[s] = (tdot[s] / (qn * kn)) * scores[s];
        }

        // top-k, descending, ties -> lowest index (strict > keeps first max)
        bool used[NSLOT];
#pragma unroll
        for (int s = 0; s < NSLOT; ++s) used[s] = false;
        float tsc[NSLOT];
        int   tix[NSLOT];
        for (int j = 0; j < k; ++j) {
            float best = -INFINITY;
            int bi = 0;
            for (int s = 0; s < NSLOT; ++s) {
                if (!used[s] && comb[s] > best) { best = comb[s]; bi = s; }
            }
            used[bi] = true;
            tsc[j] = best;
            tix[j] = bi;
        }

        // softmax(top/TEMP) with max subtraction (tsc[0] is the max)
        float m = tsc[0];
        float esum = 0.f;
        float attn[NSLOT];
        for (int j = 0; j < k; ++j) {
            attn[j] = expf((tsc[j] - m) * 10.0f);   // 1/TEMP = 10
            esum += attn[j];
        }
        float inv = 1.0f / esum;

        int hit = (ssum != 0.0f) ? 1 : 0;
        sh_hit = hit;
        float wsum = 0.f;
        for (int j = 0; j < k; ++j) {
            sh_attn[j] = attn[j] * inv;
            sh_idx[j]  = tix[j];
            wsum += tsc[j];
        }
        out_w[i] = hit ? (wsum / (float)k) : 0.0f;
    }
    __syncthreads();

    // ---- pass 2: retrieved = sum_j attn[j] * vals[idx[j]] ----
    if (sh_hit) {
        float a[NSLOT];
        int   vi[NSLOT];
        for (int j = 0; j < k; ++j) { a[j] = sh_attn[j]; vi[j] = sh_idx[j]; }
        for (int idx = tid; idx < n4; idx += THREADS) {
            float4 acc = make_float4(0.f, 0.f, 0.f, 0.f);
            for (int j = 0; j < k; ++j) {
                float4 v = v4[vi[j] * n4 + idx];
                acc.x += a[j] * v.x;
                acc.y += a[j] * v.y;
                acc.z += a[j] * v.z;
                acc.w += a[j] * v.w;
            }
            o4[idx] = acc;
        }
    } else {
        float4 z = make_float4(0.f, 0.f, 0.f, 0.f);
        for (int idx = tid; idx < n4; idx += THREADS) o4[idx] = z;
    }
}

extern "C" void kernel_launch(void* const* d_in, const int* in_sizes, int n_in,
                              void* d_out, int out_size, void* d_ws, size_t ws_size,
                              hipStream_t stream) {
    const float* query   = (const float*)d_in[0];
    const int*   labels  = (const int*)d_in[1];
    const float* mkeys   = (const float*)d_in[2];
    const float* mvals   = (const float*)d_in[3];
    const float* qscores = (const float*)d_in[4];
    const int*   topk    = (const int*)d_in[5];

    const int B = in_sizes[1];
    const int D = in_sizes[0] / B;

    float* out_ret = (float*)d_out;
    float* out_w   = out_ret + (size_t)B * D;

    mb_kernel<<<dim3(B), dim3(THREADS), 0, stream>>>(
        query, labels, mkeys, mvals, qscores, topk, out_ret, out_w, D);
}

// Round 2
// 49.930 us; speedup vs baseline: 1.0403x; 1.0403x over previous
//
#include <hip/hip_runtime.h>
#include <math.h>

#define THREADS 256
#define WPB 4          // waves (=samples) per block
#define NSLOT 5
#define EPSF 1e-8f

template<int N4T>
__global__ __launch_bounds__(THREADS, 4) void mb_wave_kernel(
    const float* __restrict__ query,    // B x D
    const int*   __restrict__ labels,   // B
    const float* __restrict__ mkeys,    // C x S x D
    const float* __restrict__ mvals,    // C x S x D
    const float* __restrict__ qscores,  // C x S
    const int*   __restrict__ topk_p,   // scalar
    float* __restrict__ out_ret,        // B x D
    float* __restrict__ out_w,          // B
    int B, int n4_rt)
{
    const int tid  = threadIdx.x;
    const int lane = tid & 63;
    const int wave = tid >> 6;
    const int i    = blockIdx.x * WPB + wave;
    if (i >= B) return;

    const int n4 = (N4T > 0) ? N4T : n4_rt;
    const int c  = labels[i];

    int k = topk_p[0];
    if (k > NSLOT) k = NSLOT;
    if (k < 1) k = 1;

    const float4* q4 = reinterpret_cast<const float4*>(query) + (size_t)i * n4;
    const float4* k4 = reinterpret_cast<const float4*>(mkeys) + (size_t)c * NSLOT * n4;
    const float4* v4 = reinterpret_cast<const float4*>(mvals) + (size_t)c * NSLOT * n4;
    float4*       o4 = reinterpret_cast<float4*>(out_ret) + (size_t)i * n4;

    // ---- pass 1: qq, dot[s], kk[s] in one sweep over q + 5 key rows ----
    float qq = 0.f;
    float dot[NSLOT], kk[NSLOT];
#pragma unroll
    for (int s = 0; s < NSLOT; ++s) { dot[s] = 0.f; kk[s] = 0.f; }

    auto body1 = [&](int idx) {
        float4 q = q4[idx];
        qq = fmaf(q.x, q.x, fmaf(q.y, q.y, fmaf(q.z, q.z, fmaf(q.w, q.w, qq))));
#pragma unroll
        for (int s = 0; s < NSLOT; ++s) {
            float4 kv = k4[s * n4 + idx];
            dot[s] = fmaf(q.x, kv.x, fmaf(q.y, kv.y, fmaf(q.z, kv.z, fmaf(q.w, kv.w, dot[s]))));
            kk[s]  = fmaf(kv.x, kv.x, fmaf(kv.y, kv.y, fmaf(kv.z, kv.z, fmaf(kv.w, kv.w, kk[s]))));
        }
    };
    if constexpr (N4T > 0) {
#pragma unroll
        for (int j = 0; j < N4T / 64; ++j) body1(lane + j * 64);
    } else {
        for (int idx = lane; idx < n4; idx += 64) body1(idx);
    }

    // ---- butterfly reduce: every lane ends with full sums ----
#pragma unroll
    for (int off = 1; off < 64; off <<= 1) {
        qq += __shfl_xor(qq, off);
#pragma unroll
        for (int s = 0; s < NSLOT; ++s) {
            dot[s] += __shfl_xor(dot[s], off);
            kk[s]  += __shfl_xor(kk[s], off);
        }
    }

    // ---- scalar epilogue, computed redundantly on all 64 lanes ----
    float qn = fmaxf(sqrtf(qq), EPSF);

    float scores[NSLOT];
    float ssum = 0.f;
#pragma unroll
    for (int s = 0; s < NSLOT; ++s) {
        scores[s] = qscores[(size_t)c * NSLOT + s];
        ssum += scores[s];
    }

    float comb[NSLOT];
#pragma unroll
    for (int s = 0; s < NSLOT; ++s) {
        float kn = fmaxf(sqrtf(kk[s]), EPSF);
        comb[s] = (dot[s] / (qn * kn)) * scores[s];
    }

    // top-k descending, ties -> lowest index (strict > keeps first max)
    bool used[NSLOT];
#pragma unroll
    for (int s = 0; s < NSLOT; ++s) used[s] = false;
    float tsc[NSLOT];
    int   tix[NSLOT];
#pragma unroll
    for (int j = 0; j < NSLOT; ++j) {
        if (j < k) {
            float best = -INFINITY;
            int bi = 0;
#pragma unroll
            for (int s = 0; s < NSLOT; ++s) {
                if (!used[s] && comb[s] > best) { best = comb[s]; bi = s; }
            }
            used[bi] = true;
            tsc[j] = best;
            tix[j] = bi;
        }
    }

    // softmax(top/TEMP), max-subtracted (tsc[0] is the max)
    const bool hit = (ssum != 0.0f);
    float m = tsc[0];
    float esum = 0.f, wsum = 0.f;
    float a[NSLOT];
#pragma unroll
    for (int j = 0; j < NSLOT; ++j) {
        if (j < k) {
            a[j] = __expf((tsc[j] - m) * 10.0f);   // 1/TEMP
            esum += a[j];
            wsum += tsc[j];
        } else {
            a[j] = 0.f;
        }
    }
    float inv = hit ? (1.0f / esum) : 0.0f;        // !hit -> all weights 0 -> zero output
#pragma unroll
    for (int j = 0; j < NSLOT; ++j) a[j] *= inv;

    if (lane == 0) out_w[i] = hit ? (wsum / (float)k) : 0.0f;

    // ---- pass 2: retrieved = sum_j a[j] * vals[tix[j]] ----
    auto body2 = [&](int idx) {
        float4 acc = make_float4(0.f, 0.f, 0.f, 0.f);
#pragma unroll
        for (int j = 0; j < NSLOT; ++j) {
            if (j < k) {
                float4 v = v4[tix[j] * n4 + idx];
                acc.x = fmaf(a[j], v.x, acc.x);
                acc.y = fmaf(a[j], v.y, acc.y);
                acc.z = fmaf(a[j], v.z, acc.z);
                acc.w = fmaf(a[j], v.w, acc.w);
            }
        }
        o4[idx] = acc;
    };
    if constexpr (N4T > 0) {
#pragma unroll
        for (int j = 0; j < N4T / 64; ++j) body2(lane + j * 64);
    } else {
        for (int idx = lane; idx < n4; idx += 64) body2(idx);
    }
}

extern "C" void kernel_launch(void* const* d_in, const int* in_sizes, int n_in,
                              void* d_out, int out_size, void* d_ws, size_t ws_size,
                              hipStream_t stream) {
    const float* query   = (const float*)d_in[0];
    const int*   labels  = (const int*)d_in[1];
    const float* mkeys   = (const float*)d_in[2];
    const float* mvals   = (const float*)d_in[3];
    const float* qscores = (const float*)d_in[4];
    const int*   topk    = (const int*)d_in[5];

    const int B  = in_sizes[1];
    const int D  = in_sizes[0] / B;
    const int n4 = D >> 2;

    float* out_ret = (float*)d_out;
    float* out_w   = out_ret + (size_t)B * D;

    dim3 grid((B + WPB - 1) / WPB), block(THREADS);
    if (D == 2048) {
        mb_wave_kernel<512><<<grid, block, 0, stream>>>(
            query, labels, mkeys, mvals, qscores, topk, out_ret, out_w, B, n4);
    } else if (D == 1024) {
        mb_wave_kernel<256><<<grid, block, 0, stream>>>(
            query, labels, mkeys, mvals, qscores, topk, out_ret, out_w, B, n4);
    } else {
        mb_wave_kernel<0><<<grid, block, 0, stream>>>(
            query, labels, mkeys, mvals, qscores, topk, out_ret, out_w, B, n4);
    }
}